// Round 2
// baseline (265.878 us; speedup 1.0000x reference)
//
#include <hip/hip_runtime.h>

// Problem constants (fixed by the reference setup):
constexpr int Bv = 16, Hv = 768, Wv = 2048;
constexpr int ROWS_PER_BLOCK = 4;                 // Hv % 4 == 0 -> block stays in one image
constexpr int NROWS   = Bv * Hv;                  // 12288
constexpr int NBLOCKS = NROWS / ROWS_PER_BLOCK;   // 3072 (ws need: 3072*8 B = 24 KiB)

typedef float f32x4 __attribute__((ext_vector_type(4)));

// Zero-initialized at module load; monotonically increasing ticket.
// Each launch adds exactly NBLOCKS, so "t % NBLOCKS == NBLOCKS-1" identifies
// the last-arriving block of THIS launch — robust across graph replays and
// rocprof counter-collection replays without any reset memset.
__device__ unsigned long long g_ticket = 0ull;

__global__ __launch_bounds__(256) void balancer_fused(
    const float* __restrict__ loss,
    const float* __restrict__ boxes,
    const int*   __restrict__ num_gt,
    double*      __restrict__ partials,
    float*       __restrict__ out)
{
    const int tid  = threadIdx.x;
    const int lane = tid & 63;
    const int wid  = tid >> 6;
    const int row0 = blockIdx.x * ROWS_PER_BLOCK;
    const int b    = row0 / Hv;                   // block-uniform image index
    const int h0   = row0 - b * Hv;               // first in-image row of this block
    const int n    = num_gt[0];

    // ---- Issue ALL loss loads up front (nontemporal: streamed exactly once,
    // 96 MiB >> 32 MiB L2 -> don't evict the reused box lines). No barrier
    // ever separates these from their uses, so the compiler waits vmcnt
    // incrementally per row instead of draining the queue.
    f32x4 vbuf[ROWS_PER_BLOCK][2];
    const f32x4* base4 = (const f32x4*)(loss + (size_t)row0 * Wv);
    #pragma unroll
    for (int r = 0; r < ROWS_PER_BLOCK; ++r) {
        #pragma unroll
        for (int it = 0; it < 2; ++it)
            vbuf[r][it] = __builtin_nontemporal_load(&base4[r * (Wv / 4) + it * 256 + tid]);
    }

    float sum = 0.0f;
    const int c0 = tid * 4;                       // chunk A col base (it=0)
    const int c1 = 1024 + tid * 4;                // chunk B col base (it=1)

    if (n <= 64) {
        // ---- Wave-redundant ballot compaction: every wave computes the SAME
        // per-row active mask over its per-lane box -> nothing to share, so
        // NO LDS, NO atomics, NO __syncthreads before compute.
        int u1 = 0, u2 = 0, v1 = 0, v2 = 0;       // lanes >= n: empty ranges
        if (lane < n) {
            const f32x4 bx = ((const f32x4*)boxes)[b * n + lane];
            u1 = (int)floorf(bx.x);
            v1 = (int)floorf(bx.y);
            u2 = (int)ceilf(bx.z);
            v2 = (int)ceilf(bx.w);
        }

        #pragma unroll
        for (int r = 0; r < ROWS_PER_BLOCK; ++r) {
            const int h = h0 + r;
            unsigned long long mask = __ballot(h >= v1 && h < v2);  // E[popc] ~ 4.3
            bool fa0 = false, fa1 = false, fa2 = false, fa3 = false;
            bool fb0 = false, fb1 = false, fb2 = false, fb3 = false;
            while (mask) {                        // wave-uniform trip count
                const int src = __builtin_ctzll(mask);
                mask &= mask - 1;
                const int a = __shfl(u1, src, 64);
                const int e = __shfl(u2, src, 64);
                fa0 |= (c0     >= a) & (c0     < e);
                fa1 |= (c0 + 1 >= a) & (c0 + 1 < e);
                fa2 |= (c0 + 2 >= a) & (c0 + 2 < e);
                fa3 |= (c0 + 3 >= a) & (c0 + 3 < e);
                fb0 |= (c1     >= a) & (c1     < e);
                fb1 |= (c1 + 1 >= a) & (c1 + 1 < e);
                fb2 |= (c1 + 2 >= a) & (c1 + 2 < e);
                fb3 |= (c1 + 3 >= a) & (c1 + 3 < e);
            }
            // Same per-thread accumulation order as all prior versions:
            // r outer, it=0 (x,y,z,w) then it=1 (x,y,z,w) -> bit-identical.
            const f32x4 va = vbuf[r][0];
            sum += va.x * (fa0 ? 13.0f : 1.0f);
            sum += va.y * (fa1 ? 13.0f : 1.0f);
            sum += va.z * (fa2 ? 13.0f : 1.0f);
            sum += va.w * (fa3 ? 13.0f : 1.0f);
            const f32x4 vb = vbuf[r][1];
            sum += vb.x * (fb0 ? 13.0f : 1.0f);
            sum += vb.y * (fb1 ? 13.0f : 1.0f);
            sum += vb.z * (fb2 ? 13.0f : 1.0f);
            sum += vb.w * (fb3 ? 13.0f : 1.0f);
        }
    } else {
        // General fallback (n > 64; never hit in this setup): brute-force
        // per-box tests straight from global (L2-resident).
        #pragma unroll
        for (int r = 0; r < ROWS_PER_BLOCK; ++r) {
            const int h = h0 + r;
            bool fa0 = false, fa1 = false, fa2 = false, fa3 = false;
            bool fb0 = false, fb1 = false, fb2 = false, fb3 = false;
            for (int i = 0; i < n; ++i) {
                const f32x4 bx = ((const f32x4*)boxes)[b * n + i];
                const int v1 = (int)floorf(bx.y);
                const int v2 = (int)ceilf(bx.w);
                if (h >= v1 && h < v2) {
                    const int a = (int)floorf(bx.x);
                    const int e = (int)ceilf(bx.z);
                    fa0 |= (c0     >= a) & (c0     < e);
                    fa1 |= (c0 + 1 >= a) & (c0 + 1 < e);
                    fa2 |= (c0 + 2 >= a) & (c0 + 2 < e);
                    fa3 |= (c0 + 3 >= a) & (c0 + 3 < e);
                    fb0 |= (c1     >= a) & (c1     < e);
                    fb1 |= (c1 + 1 >= a) & (c1 + 1 < e);
                    fb2 |= (c1 + 2 >= a) & (c1 + 2 < e);
                    fb3 |= (c1 + 3 >= a) & (c1 + 3 < e);
                }
            }
            const f32x4 va = vbuf[r][0];
            sum += va.x * (fa0 ? 13.0f : 1.0f);
            sum += va.y * (fa1 ? 13.0f : 1.0f);
            sum += va.z * (fa2 ? 13.0f : 1.0f);
            sum += va.w * (fa3 ? 13.0f : 1.0f);
            const f32x4 vb = vbuf[r][1];
            sum += vb.x * (fb0 ? 13.0f : 1.0f);
            sum += vb.y * (fb1 ? 13.0f : 1.0f);
            sum += vb.z * (fb2 ? 13.0f : 1.0f);
            sum += vb.w * (fb3 ? 13.0f : 1.0f);
        }
    }

    // ---- Wave-64 shuffle reduction (fp32 leaves, tiny magnitudes -> safe).
    for (int off = 32; off > 0; off >>= 1)
        sum += __shfl_down(sum, off, 64);

    __shared__ float s_wsum[4];
    __shared__ bool  s_last;
    if (lane == 0) s_wsum[wid] = sum;
    __syncthreads();                              // first barrier in the kernel

    if (tid == 0) {
        double d = 0.0;
        #pragma unroll
        for (int wq = 0; wq < 4; ++wq) d += (double)s_wsum[wq];
        // Agent-scope atomic store: visible across non-coherent XCD L2s.
        __hip_atomic_store(&partials[blockIdx.x], d,
                           __ATOMIC_RELAXED, __HIP_MEMORY_SCOPE_AGENT);
        const unsigned long long t =
            __hip_atomic_fetch_add(&g_ticket, 1ull,
                                   __ATOMIC_ACQ_REL, __HIP_MEMORY_SCOPE_AGENT);
        s_last = ((t % (unsigned long long)NBLOCKS) ==
                  (unsigned long long)(NBLOCKS - 1));
    }
    __syncthreads();

    if (s_last) {
        // Last-arriving block reduces all partials in the SAME fixed order as
        // the old balancer_reduce kernel -> deterministic, bit-identical.
        double s = 0.0;
        for (int i = tid; i < NBLOCKS; i += 256)
            s += __hip_atomic_load(&partials[i],
                                   __ATOMIC_RELAXED, __HIP_MEMORY_SCOPE_AGENT);
        for (int off = 32; off > 0; off >>= 1)
            s += __shfl_down(s, off, 64);
        __shared__ double sh[4];
        if (lane == 0) sh[wid] = s;
        __syncthreads();
        if (tid == 0) {
            const double t = sh[0] + sh[1] + sh[2] + sh[3];
            out[0] = (float)(t / (double)((long long)Bv * Hv * Wv));
        }
    }
}

extern "C" void kernel_launch(void* const* d_in, const int* in_sizes, int n_in,
                              void* d_out, int out_size, void* d_ws, size_t ws_size,
                              hipStream_t stream) {
    const float* loss   = (const float*)d_in[0];
    const float* boxes  = (const float*)d_in[1];
    const int*   num_gt = (const int*)d_in[2];
    double*      partials = (double*)d_ws;        // 24 KiB needed
    float*       out      = (float*)d_out;

    balancer_fused<<<NBLOCKS, 256, 0, stream>>>(loss, boxes, num_gt, partials, out);
}

// Round 4
// 158.018 us; speedup vs baseline: 1.6826x; 1.6826x over previous
//
#include <hip/hip_runtime.h>

// Problem constants (fixed by the reference setup):
constexpr int Bv = 16, Hv = 768, Wv = 2048;
constexpr int ROWS_PER_BLOCK = 4;                 // Hv % 4 == 0 -> block stays in one image
constexpr int NROWS   = Bv * Hv;                  // 12288
constexpr int NBLOCKS = NROWS / ROWS_PER_BLOCK;   // 3072 (ws need: 3072*8 B = 24 KiB)

typedef float f32x4 __attribute__((ext_vector_type(4)));

// NOTE (round-2 lesson): do NOT fuse the final reduce via an agent-scope
// acq_rel ticket. With non-coherent per-XCD L2s, each release forces an
// L2 writeback/invalidate -> 3072 flushes ~ 140 us of pure latency
// (measured: 144 us/dispatch at 4% HBM, 6% VALU, even on cached replays).
// Two dispatches with plain stores cost ~4 us total and are deterministic.

__global__ __launch_bounds__(256) void balancer_main(
    const float* __restrict__ loss,
    const float* __restrict__ boxes,
    const int*   __restrict__ num_gt,
    double*      __restrict__ partials)
{
    const int tid  = threadIdx.x;
    const int lane = tid & 63;
    const int wid  = tid >> 6;
    const int row0 = blockIdx.x * ROWS_PER_BLOCK;
    const int b    = row0 / Hv;                   // block-uniform image index
    const int h0   = row0 - b * Hv;               // first in-image row of this block
    const int n    = num_gt[0];

    // ---- Issue ALL loss loads up front (nontemporal streaming hint; the
    // tensor is read exactly once). No barrier separates these from their
    // uses, so the compiler waits vmcnt incrementally per row instead of
    // draining the whole queue (round-0/1 mistake).
    f32x4 vbuf[ROWS_PER_BLOCK][2];
    const f32x4* base4 = (const f32x4*)(loss + (size_t)row0 * Wv);
    #pragma unroll
    for (int r = 0; r < ROWS_PER_BLOCK; ++r) {
        #pragma unroll
        for (int it = 0; it < 2; ++it)
            vbuf[r][it] = __builtin_nontemporal_load(&base4[r * (Wv / 4) + it * 256 + tid]);
    }

    float sum = 0.0f;
    const int c0 = tid * 4;                       // chunk A col base (it=0)
    const int c1 = 1024 + tid * 4;                // chunk B col base (it=1)

    if (n <= 64) {
        // ---- Wave-redundant ballot compaction: every wave computes the SAME
        // per-row active mask over its per-lane box -> nothing to share, so
        // NO LDS, NO atomics, NO __syncthreads before compute.
        int u1 = 0, u2 = 0, v1 = 0, v2 = 0;       // lanes >= n: empty ranges
        if (lane < n) {
            const f32x4 bx = ((const f32x4*)boxes)[b * n + lane];
            u1 = (int)floorf(bx.x);
            v1 = (int)floorf(bx.y);
            u2 = (int)ceilf(bx.z);
            v2 = (int)ceilf(bx.w);
        }

        #pragma unroll
        for (int r = 0; r < ROWS_PER_BLOCK; ++r) {
            const int h = h0 + r;
            unsigned long long mask = __ballot(h >= v1 && h < v2);  // E[popc] ~ 4.3
            bool fa0 = false, fa1 = false, fa2 = false, fa3 = false;
            bool fb0 = false, fb1 = false, fb2 = false, fb3 = false;
            while (mask) {                        // wave-uniform trip count
                const int src = __builtin_ctzll(mask);
                mask &= mask - 1;
                const int a = __shfl(u1, src, 64);
                const int e = __shfl(u2, src, 64);
                fa0 |= (c0     >= a) & (c0     < e);
                fa1 |= (c0 + 1 >= a) & (c0 + 1 < e);
                fa2 |= (c0 + 2 >= a) & (c0 + 2 < e);
                fa3 |= (c0 + 3 >= a) & (c0 + 3 < e);
                fb0 |= (c1     >= a) & (c1     < e);
                fb1 |= (c1 + 1 >= a) & (c1 + 1 < e);
                fb2 |= (c1 + 2 >= a) & (c1 + 2 < e);
                fb3 |= (c1 + 3 >= a) & (c1 + 3 < e);
            }
            // Same per-thread accumulation order as all prior versions:
            // r outer, it=0 (x,y,z,w) then it=1 (x,y,z,w) -> bit-identical.
            // (Flag ORs are order-independent, so ballot order vs the old
            // atomicAdd compaction order cannot change the result.)
            const f32x4 va = vbuf[r][0];
            sum += va.x * (fa0 ? 13.0f : 1.0f);
            sum += va.y * (fa1 ? 13.0f : 1.0f);
            sum += va.z * (fa2 ? 13.0f : 1.0f);
            sum += va.w * (fa3 ? 13.0f : 1.0f);
            const f32x4 vb = vbuf[r][1];
            sum += vb.x * (fb0 ? 13.0f : 1.0f);
            sum += vb.y * (fb1 ? 13.0f : 1.0f);
            sum += vb.z * (fb2 ? 13.0f : 1.0f);
            sum += vb.w * (fb3 ? 13.0f : 1.0f);
        }
    } else {
        // General fallback (n > 64; never hit in this setup): brute-force
        // per-box tests straight from global (L2-resident).
        #pragma unroll
        for (int r = 0; r < ROWS_PER_BLOCK; ++r) {
            const int h = h0 + r;
            bool fa0 = false, fa1 = false, fa2 = false, fa3 = false;
            bool fb0 = false, fb1 = false, fb2 = false, fb3 = false;
            for (int i = 0; i < n; ++i) {
                const f32x4 bx = ((const f32x4*)boxes)[b * n + i];
                const int v1 = (int)floorf(bx.y);
                const int v2 = (int)ceilf(bx.w);
                if (h >= v1 && h < v2) {
                    const int a = (int)floorf(bx.x);
                    const int e = (int)ceilf(bx.z);
                    fa0 |= (c0     >= a) & (c0     < e);
                    fa1 |= (c0 + 1 >= a) & (c0 + 1 < e);
                    fa2 |= (c0 + 2 >= a) & (c0 + 2 < e);
                    fa3 |= (c0 + 3 >= a) & (c0 + 3 < e);
                    fb0 |= (c1     >= a) & (c1     < e);
                    fb1 |= (c1 + 1 >= a) & (c1 + 1 < e);
                    fb2 |= (c1 + 2 >= a) & (c1 + 2 < e);
                    fb3 |= (c1 + 3 >= a) & (c1 + 3 < e);
                }
            }
            const f32x4 va = vbuf[r][0];
            sum += va.x * (fa0 ? 13.0f : 1.0f);
            sum += va.y * (fa1 ? 13.0f : 1.0f);
            sum += va.z * (fa2 ? 13.0f : 1.0f);
            sum += va.w * (fa3 ? 13.0f : 1.0f);
            const f32x4 vb = vbuf[r][1];
            sum += vb.x * (fb0 ? 13.0f : 1.0f);
            sum += vb.y * (fb1 ? 13.0f : 1.0f);
            sum += vb.z * (fb2 ? 13.0f : 1.0f);
            sum += vb.w * (fb3 ? 13.0f : 1.0f);
        }
    }

    // ---- Wave-64 shuffle reduction (fp32 leaves, tiny magnitudes -> safe).
    for (int off = 32; off > 0; off >>= 1)
        sum += __shfl_down(sum, off, 64);

    __shared__ float s_wsum[4];
    if (lane == 0) s_wsum[wid] = sum;
    __syncthreads();                              // ONLY barrier in the kernel
    if (tid == 0) {
        double d = 0.0;
        #pragma unroll
        for (int wq = 0; wq < 4; ++wq) d += (double)s_wsum[wq];
        partials[blockIdx.x] = d;                 // plain store: no atomics, deterministic
    }
}

__global__ __launch_bounds__(256) void balancer_reduce(
    const double* __restrict__ partials, float* __restrict__ out)
{
    const int tid = threadIdx.x;
    double s = 0.0;
    for (int i = tid; i < NBLOCKS; i += 256) s += partials[i];
    for (int off = 32; off > 0; off >>= 1)
        s += __shfl_down(s, off, 64);
    __shared__ double sh[4];
    if ((tid & 63) == 0) sh[tid >> 6] = s;
    __syncthreads();
    if (tid == 0) {
        const double t = sh[0] + sh[1] + sh[2] + sh[3];
        out[0] = (float)(t / (double)((long long)Bv * Hv * Wv));
    }
}

extern "C" void kernel_launch(void* const* d_in, const int* in_sizes, int n_in,
                              void* d_out, int out_size, void* d_ws, size_t ws_size,
                              hipStream_t stream) {
    const float* loss   = (const float*)d_in[0];
    const float* boxes  = (const float*)d_in[1];
    const int*   num_gt = (const int*)d_in[2];
    double*      partials = (double*)d_ws;        // 24 KiB needed
    float*       out      = (float*)d_out;

    balancer_main<<<NBLOCKS, 256, 0, stream>>>(loss, boxes, num_gt, partials);
    balancer_reduce<<<1, 256, 0, stream>>>(partials, out);
}